// Round 7
// baseline (223.043 us; speedup 1.0000x reference)
//
#include <hip/hip_runtime.h>

#define HID    128
#define VOCAB  1000
#define N_CAT  200000
#define N_CONT 150000
#define N_TXN  150000
#define F_TXN  371
#define KP     384                          // padded K in workspace B^T
#define NSTEP  12                           // 12*32 = 384 >= 371
#define OUT_TXN_BASE (N_CAT + N_CONT)

#define SLAB_ROWS 16
#define SLAB_F32  (SLAB_ROWS * F_TXN)       // 5936 floats of real data per slab
#define SLAB_PAD  6144                      // 24 groups x 256 floats (pad never read)
#define NSLAB     (N_TXN / SLAB_ROWS)       // 9375 exactly
#define A_ELEMS   ((size_t)N_TXN * F_TXN)   // 55,650,000

typedef __attribute__((ext_vector_type(4))) float f32x4;
typedef __attribute__((ext_vector_type(8))) short bf16x8;

__device__ __forceinline__ unsigned short f2bf(float x) {
    union { float f; unsigned u; } c; c.f = x;
    unsigned r = c.u + 0x7FFF + ((c.u >> 16) & 1);   // RNE
    return (unsigned short)(r >> 16);
}

__device__ __forceinline__ bf16x8 cvt8(f32x4 a, f32x4 b) {
    bf16x8 r;
    r[0] = (short)f2bf(a[0]); r[1] = (short)f2bf(a[1]);
    r[2] = (short)f2bf(a[2]); r[3] = (short)f2bf(a[3]);
    r[4] = (short)f2bf(b[0]); r[5] = (short)f2bf(b[1]);
    r[6] = (short)f2bf(b[2]); r[7] = (short)f2bf(b[3]);
    return r;
}

// ---- producer: Bt[col][k] = bf16(w[k][col]), zero-padded to KP ----
__global__ void bt_kernel(const float* __restrict__ w, unsigned short* __restrict__ bt) {
    int col = blockIdx.x;          // 0..127
    int k   = threadIdx.x;         // 0..383
    float v = (k < F_TXN) ? w[(long)k * HID + col] : 0.f;
    bt[col * KP + k] = f2bf(v);
}

// ---- fused cat gather + cont linear ----
#define CAT_BLOCKS  (N_CAT / 8)
#define CONT_BLOCKS (N_CONT / 8)
__global__ __launch_bounds__(256) void catcont_kernel(
    const float* __restrict__ tables, const int* __restrict__ tids, const int* __restrict__ vids,
    const float* __restrict__ w, const float* __restrict__ b,
    const float* __restrict__ vals, const int* __restrict__ ctids,
    float* __restrict__ out)
{
    int bid = blockIdx.x;
    if (bid < CAT_BLOCKS) {
        int tid = bid * 256 + threadIdx.x;
        int row = tid >> 5;
        int h   = (tid & 31) << 2;
        long src = ((long)tids[row] * VOCAB + vids[row]) * HID + h;
        *reinterpret_cast<f32x4*>(out + (long)row * HID + h) =
            *reinterpret_cast<const f32x4*>(tables + src);
    } else {
        int tid = (bid - CAT_BLOCKS) * 256 + threadIdx.x;
        int row = tid >> 5;
        int h   = (tid & 31) << 2;
        int t   = ctids[row];
        float v = vals[row];
        f32x4 wv = *reinterpret_cast<const f32x4*>(w + t * HID + h);
        f32x4 bv = *reinterpret_cast<const f32x4*>(b + t * HID + h);
        f32x4 r  = v * wv + bv;
        *reinterpret_cast<f32x4*>(out + (long)(N_CAT + row) * HID + h) = r;
    }
}

// ---- txn GEMM: one block per 16-row slab; reg-staged linear slab, no DMA ----
// Stage: 6 x (global_load_dwordx4 + ds_write_b128) per thread, all contiguous
// 1 KB per wave-instr. One barrier. Compute: 12 MFMA steps, B reg-direct from
// the L2-hot zero-padded B^T. Wave w owns 16 rows x cols [w*32, w*32+32).
__global__ __launch_bounds__(256) void txn_slab_kernel(
    const float* __restrict__ feats, const unsigned short* __restrict__ bt,
    const float* __restrict__ bias, float* __restrict__ out)
{
    __shared__ __align__(16) float As[SLAB_PAD];   // 24 KB, linear slab image

    const int t    = threadIdx.x;
    const int lane = t & 63;
    const int w    = t >> 6;
    const int r16  = lane & 15;
    const int kg   = lane >> 4;          // k-group: k = kg*8 + j
    const size_t S0 = (size_t)blockIdx.x * SLAB_F32;

    // ---- stage slab: As[x] = feats[S0 + x] for x in [0, SLAB_PAD) ----
    #pragma unroll
    for (int i = 0; i < 6; ++i) {
        int idx = (i * 4 + w) * 256 + lane * 4;          // 16B-aligned (S0%4==0)
        size_t ge = S0 + (size_t)idx;
        if (ge > A_ELEMS - 4) ge = A_ELEMS - 4;          // padding/last-slab clamp
        f32x4 v = *reinterpret_cast<const f32x4*>(feats + ge);
        *reinterpret_cast<f32x4*>(&As[idx]) = v;
    }
    __syncthreads();

    // ---- invariant B pointers + bias, col = w*32 + nf*16 + r16 ----
    const unsigned short* bp[2];
    float bv[2];
    #pragma unroll
    for (int nf = 0; nf < 2; ++nf) {
        int col = w * 32 + nf * 16 + r16;
        bp[nf]  = bt + (size_t)col * KP + kg * 8;
        bv[nf]  = bias[col];
    }

    f32x4 acc[2];
    acc[0] = f32x4{0.f, 0.f, 0.f, 0.f};
    acc[1] = f32x4{0.f, 0.f, 0.f, 0.f};

    const float* Ab = &As[r16 * F_TXN];

    #pragma unroll
    for (int s = 0; s < NSTEP; ++s) {
        bf16x8 af;
        if (s < NSTEP - 1) {
            const float* p = Ab + s * 32 + kg * 8;
            f32x4 lo{p[0], p[1], p[2], p[3]};
            f32x4 hi{p[4], p[5], p[6], p[7]};
            af = cvt8(lo, hi);
        } else {                           // tail: zero-guard k >= 371
            float v[8];
            #pragma unroll
            for (int j = 0; j < 8; ++j) {
                int k = s * 32 + kg * 8 + j;
                v[j] = (k < F_TXN) ? Ab[k] : 0.f;
            }
            f32x4 lo{v[0], v[1], v[2], v[3]};
            f32x4 hi{v[4], v[5], v[6], v[7]};
            af = cvt8(lo, hi);
        }
        #pragma unroll
        for (int nf = 0; nf < 2; ++nf) {
            bf16x8 bfrag = *reinterpret_cast<const bf16x8*>(bp[nf] + s * 32);
            acc[nf] = __builtin_amdgcn_mfma_f32_16x16x32_bf16(af, bfrag, acc[nf], 0, 0, 0);
        }
    }

    // ---- store: C row = kg*4 + j, col = w*32 + nf*16 + r16 ----
    long R0 = (long)blockIdx.x * SLAB_ROWS;
    #pragma unroll
    for (int nf = 0; nf < 2; ++nf) {
        int col = w * 32 + nf * 16 + r16;
        long rb = R0 + kg * 4;
        #pragma unroll
        for (int j = 0; j < 4; ++j) {
            long r = rb + j;
            out[(OUT_TXN_BASE + r) * HID + col] = acc[nf][j] + bv[nf];
        }
    }
}

extern "C" void kernel_launch(void* const* d_in, const int* in_sizes, int n_in,
                              void* d_out, int out_size, void* d_ws, size_t ws_size,
                              hipStream_t stream) {
    const float* cat_tables    = (const float*)d_in[0];
    const float* cont_w        = (const float*)d_in[1];
    const float* cont_b        = (const float*)d_in[2];
    const float* txn_w         = (const float*)d_in[3];
    const float* txn_b         = (const float*)d_in[4];
    const float* txn_feats     = (const float*)d_in[5];
    const float* cont_values   = (const float*)d_in[6];
    const int*   cat_type_ids  = (const int*)d_in[7];
    const int*   cat_value_ids = (const int*)d_in[8];
    const int*   cont_type_ids = (const int*)d_in[9];
    float* out = (float*)d_out;
    unsigned short* bt = (unsigned short*)d_ws;   // 128*384*2 = 96 KB

    bt_kernel<<<HID, KP, 0, stream>>>(txn_w, bt);
    txn_slab_kernel<<<NSLAB, 256, 0, stream>>>(txn_feats, bt, txn_b, out);
    catcont_kernel<<<CAT_BLOCKS + CONT_BLOCKS, 256, 0, stream>>>(
        cat_tables, cat_type_ids, cat_value_ids,
        cont_w, cont_b, cont_values, cont_type_ids, out);
}

// Round 8
// 135.214 us; speedup vs baseline: 1.6496x; 1.6496x over previous
//
#include <hip/hip_runtime.h>

#define HID    128
#define VOCAB  1000
#define N_CAT  200000
#define N_CONT 150000
#define N_TXN  150000
#define F_TXN  371
#define KP     384                           // padded K in workspace B^T
#define NSTEP  12                            // 12*32 = 384 >= 371
#define OUT_TXN_BASE (N_CAT + N_CONT)

#define SLAB_ROWS   16
#define SLAB_F32    (SLAB_ROWS * F_TXN)      // 5936 floats = 1484 x 16B chunks exactly
#define SLAB_CHUNKS (SLAB_F32 / 4)           // 1484
#define LROW        392                      // LDS row stride (shorts) = 49 x 16B chunks (odd -> bank rotation)
#define SLAB_SHORTS (SLAB_ROWS * LROW)       // 6272 shorts = 12544 B
#define NSLAB       (N_TXN / SLAB_ROWS)      // 9375 exactly
#define PBLK        768

typedef __attribute__((ext_vector_type(4))) float f32x4;
typedef __attribute__((ext_vector_type(8))) short bf16x8;

__device__ __forceinline__ unsigned short f2bf(float x) {
    union { float f; unsigned u; } c; c.f = x;
    unsigned r = c.u + 0x7FFF + ((c.u >> 16) & 1);   // RNE
    return (unsigned short)(r >> 16);
}

// ---- producer: Bt[col][k] = bf16(w[k][col]), zero-padded to KP ----
__global__ void bt_kernel(const float* __restrict__ w, unsigned short* __restrict__ bt) {
    int col = blockIdx.x;          // 0..127
    int k   = threadIdx.x;         // 0..383
    float v = (k < F_TXN) ? w[(long)k * HID + col] : 0.f;
    bt[col * KP + k] = f2bf(v);
}

// ---- fused cat gather + cont linear (validated) ----
#define CAT_BLOCKS  (N_CAT / 8)
#define CONT_BLOCKS (N_CONT / 8)
__global__ __launch_bounds__(256) void catcont_kernel(
    const float* __restrict__ tables, const int* __restrict__ tids, const int* __restrict__ vids,
    const float* __restrict__ w, const float* __restrict__ b,
    const float* __restrict__ vals, const int* __restrict__ ctids,
    float* __restrict__ out)
{
    int bid = blockIdx.x;
    if (bid < CAT_BLOCKS) {
        int tid = bid * 256 + threadIdx.x;
        int row = tid >> 5;
        int h   = (tid & 31) << 2;
        long src = ((long)tids[row] * VOCAB + vids[row]) * HID + h;
        *reinterpret_cast<f32x4*>(out + (long)row * HID + h) =
            *reinterpret_cast<const f32x4*>(tables + src);
    } else {
        int tid = (bid - CAT_BLOCKS) * 256 + threadIdx.x;
        int row = tid >> 5;
        int h   = (tid & 31) << 2;
        int t   = ctids[row];
        float v = vals[row];
        f32x4 wv = *reinterpret_cast<const f32x4*>(w + t * HID + h);
        f32x4 bv = *reinterpret_cast<const f32x4*>(b + t * HID + h);
        f32x4 r  = v * wv + bv;
        *reinterpret_cast<f32x4*>(out + (long)(N_CAT + row) * HID + h) = r;
    }
}

// ---- persistent txn GEMM: B in registers (loaded ONCE), dbuf bf16 LDS slabs ----
__global__ __launch_bounds__(256) void txn_persist_kernel(
    const float* __restrict__ feats, const unsigned short* __restrict__ bt,
    const float* __restrict__ bias, float* __restrict__ out)
{
    __shared__ __align__(16) unsigned short Alds[2 * SLAB_SHORTS];   // 25088 B

    const int t    = threadIdx.x;
    const int lane = t & 63;
    const int w    = t >> 6;
    const int r16  = lane & 15;
    const int kg   = lane >> 4;

    // ---- B fragments into registers, once per block (kills the bt hotspot) ----
    bf16x8 Bf0[NSTEP], Bf1[NSTEP];
    float bv0, bv1;
    {
        int c0 = w * 32 + r16, c1 = c0 + 16;
        bv0 = bias[c0]; bv1 = bias[c1];
        const unsigned short* p0 = bt + (size_t)c0 * KP + kg * 8;
        const unsigned short* p1 = bt + (size_t)c1 * KP + kg * 8;
        #pragma unroll
        for (int s = 0; s < NSTEP; ++s) {
            Bf0[s] = *reinterpret_cast<const bf16x8*>(p0 + s * 32);
            Bf1[s] = *reinterpret_cast<const bf16x8*>(p1 + s * 32);
        }
    }

    // ---- fixed staging geometry: thread t owns chunks q = i*256+t (16B each) ----
    bool sval[6];
    unsigned wa0[6], wa1[6];                 // packed LDS short-addresses (2x16b each)
    #pragma unroll
    for (int i = 0; i < 6; ++i) {
        int q = i * 256 + t;
        sval[i] = (q < SLAB_CHUNKS);
        int qq = sval[i] ? q : 0;
        unsigned a[4];
        #pragma unroll
        for (int j = 0; j < 4; ++j) {
            int e   = qq * 4 + j;            // float index within slab
            int r   = e / F_TXN;             // row 0..15 (magic-div)
            int col = e - r * F_TXN;
            a[j] = (unsigned)(r * LROW + col);
        }
        wa0[i] = a[0] | (a[1] << 16);
        wa1[i] = a[2] | (a[3] << 16);
    }

    // ---- zero never-written cols 371..383 (read at s=11; B=0 there, avoid NaN*0) ----
    for (int z = t; z < 2 * SLAB_ROWS * (KP - F_TXN); z += 256) {
        int b  = z / (SLAB_ROWS * (KP - F_TXN));
        int rm = z - b * (SLAB_ROWS * (KP - F_TXN));
        int r  = rm / (KP - F_TXN);
        int cc = rm - r * (KP - F_TXN);
        Alds[b * SLAB_SHORTS + r * LROW + F_TXN + cc] = 0;
    }

    f32x4 ar[6];
    auto gload = [&](int sl) {
        size_t S0 = (size_t)sl * SLAB_F32;   // 16B-aligned; slab is exactly 1484 chunks
        #pragma unroll
        for (int i = 0; i < 6; ++i)
            if (sval[i])
                ar[i] = *reinterpret_cast<const f32x4*>(feats + S0 + (size_t)(i * 256 + t) * 4);
    };
    auto swrite = [&](int buf) {
        unsigned short* dst = Alds + buf * SLAB_SHORTS;
        #pragma unroll
        for (int i = 0; i < 6; ++i)
            if (sval[i]) {
                dst[wa0[i] & 0xffffu] = f2bf(ar[i][0]);
                dst[wa0[i] >> 16]     = f2bf(ar[i][1]);
                dst[wa1[i] & 0xffffu] = f2bf(ar[i][2]);
                dst[wa1[i] >> 16]     = f2bf(ar[i][3]);
            }
    };

    const int bid = blockIdx.x;
    gload(bid);
    swrite(0);
    __syncthreads();                          // prologue: full drain once is fine

    int cur = 0;
    #pragma unroll 1
    for (int sl = bid; sl < NSLAB; sl += PBLK) {
        int  nxt      = sl + PBLK;
        bool have_nxt = (nxt < NSLAB);
        if (have_nxt) gload(nxt);             // HBM latency hides under compute

        f32x4 acc0 = f32x4{0.f, 0.f, 0.f, 0.f};
        f32x4 acc1 = f32x4{0.f, 0.f, 0.f, 0.f};
        const unsigned short* Ar = Alds + cur * SLAB_SHORTS + r16 * LROW;
        #pragma unroll
        for (int s = 0; s < NSTEP; ++s) {     // 16B-aligned, conflict-free b128 reads
            bf16x8 af = *reinterpret_cast<const bf16x8*>(Ar + s * 32 + kg * 8);
            acc0 = __builtin_amdgcn_mfma_f32_16x16x32_bf16(af, Bf0[s], acc0, 0, 0, 0);
            acc1 = __builtin_amdgcn_mfma_f32_16x16x32_bf16(af, Bf1[s], acc1, 0, 0, 0);
        }

        if (have_nxt) swrite(cur ^ 1);        // waits only the 6 loads (in-order vmcnt)

        {   // C stores: issued last, fly across the raw barrier (no vmcnt drain)
            long R0 = (long)sl * SLAB_ROWS + kg * 4;
            int  c0 = w * 32 + r16;
            #pragma unroll
            for (int j = 0; j < 4; ++j) {
                float* o = out + (OUT_TXN_BASE + R0 + j) * HID;
                o[c0]      = acc0[j] + bv0;
                o[c0 + 16] = acc1[j] + bv1;
            }
        }

        asm volatile("s_waitcnt lgkmcnt(0)" ::: "memory");   // LDS writes visible
        __builtin_amdgcn_s_barrier();
        __builtin_amdgcn_sched_barrier(0);
        cur ^= 1;
    }
}

extern "C" void kernel_launch(void* const* d_in, const int* in_sizes, int n_in,
                              void* d_out, int out_size, void* d_ws, size_t ws_size,
                              hipStream_t stream) {
    const float* cat_tables    = (const float*)d_in[0];
    const float* cont_w        = (const float*)d_in[1];
    const float* cont_b        = (const float*)d_in[2];
    const float* txn_w         = (const float*)d_in[3];
    const float* txn_b         = (const float*)d_in[4];
    const float* txn_feats     = (const float*)d_in[5];
    const float* cont_values   = (const float*)d_in[6];
    const int*   cat_type_ids  = (const int*)d_in[7];
    const int*   cat_value_ids = (const int*)d_in[8];
    const int*   cont_type_ids = (const int*)d_in[9];
    float* out = (float*)d_out;
    unsigned short* bt = (unsigned short*)d_ws;   // 128*384*2 = 96 KB

    bt_kernel<<<HID, KP, 0, stream>>>(txn_w, bt);
    txn_persist_kernel<<<PBLK, 256, 0, stream>>>(txn_feats, bt, txn_b, out);
    catcont_kernel<<<CAT_BLOCKS + CONT_BLOCKS, 256, 0, stream>>>(
        cat_tables, cat_type_ids, cat_value_ids,
        cont_w, cont_b, cont_values, cont_type_ids, out);
}

// Round 9
// 134.243 us; speedup vs baseline: 1.6615x; 1.0072x over previous
//
#include <hip/hip_runtime.h>

#define HID    128
#define VOCAB  1000
#define N_CAT  200000
#define N_CONT 150000
#define N_TXN  150000
#define F_TXN  371
#define KP     384                           // padded K in workspace B^T
#define NSTEP  12                            // 12*32 = 384 >= 371
#define OUT_TXN_BASE (N_CAT + N_CONT)

#define SLAB_ROWS   16
#define SLAB_F32    (SLAB_ROWS * F_TXN)      // 5936 floats = 1484 x 16B chunks exactly
#define SLAB_CHUNKS (SLAB_F32 / 4)           // 1484
#define LROW        392                      // LDS row stride (shorts), odd 16B-chunk count
#define SLAB_SHORTS (SLAB_ROWS * LROW)       // 6272 shorts = 12544 B
#define NSLAB       (N_TXN / SLAB_ROWS)      // 9375 exactly
#define PBLK        512                      // == resident capacity at 2 blocks/CU
#define CLSLAB(x)   ((x) < NSLAB ? (x) : (NSLAB - 1))

typedef __attribute__((ext_vector_type(4))) float f32x4;
typedef __attribute__((ext_vector_type(8))) short bf16x8;

__device__ __forceinline__ unsigned short f2bf(float x) {
    union { float f; unsigned u; } c; c.f = x;
    unsigned r = c.u + 0x7FFF + ((c.u >> 16) & 1);   // RNE
    return (unsigned short)(r >> 16);
}

// ---- producer: Bt[col][k] = bf16(w[k][col]), zero-padded to KP ----
__global__ void bt_kernel(const float* __restrict__ w, unsigned short* __restrict__ bt) {
    int col = blockIdx.x;          // 0..127
    int k   = threadIdx.x;         // 0..383
    float v = (k < F_TXN) ? w[(long)k * HID + col] : 0.f;
    bt[col * KP + k] = f2bf(v);
}

// ---- fused cat gather + cont linear (validated, ~BW floor) ----
#define CAT_BLOCKS  (N_CAT / 8)
#define CONT_BLOCKS (N_CONT / 8)
__global__ __launch_bounds__(256) void catcont_kernel(
    const float* __restrict__ tables, const int* __restrict__ tids, const int* __restrict__ vids,
    const float* __restrict__ w, const float* __restrict__ b,
    const float* __restrict__ vals, const int* __restrict__ ctids,
    float* __restrict__ out)
{
    int bid = blockIdx.x;
    if (bid < CAT_BLOCKS) {
        int tid = bid * 256 + threadIdx.x;
        int row = tid >> 5;
        int h   = (tid & 31) << 2;
        long src = ((long)tids[row] * VOCAB + vids[row]) * HID + h;
        *reinterpret_cast<f32x4*>(out + (long)row * HID + h) =
            *reinterpret_cast<const f32x4*>(tables + src);
    } else {
        int tid = (bid - CAT_BLOCKS) * 256 + threadIdx.x;
        int row = tid >> 5;
        int h   = (tid & 31) << 2;
        int t   = ctids[row];
        float v = vals[row];
        f32x4 wv = *reinterpret_cast<const f32x4*>(w + t * HID + h);
        f32x4 bv = *reinterpret_cast<const f32x4*>(b + t * HID + h);
        f32x4 r  = v * wv + bv;
        *reinterpret_cast<f32x4*>(out + (long)(N_CAT + row) * HID + h) = r;
    }
}

// ---- persistent txn GEMM: B in regs, depth-2 reg prefetch, dbuf bf16 LDS ----
__global__ __launch_bounds__(256) void txn_persist_kernel(
    const float* __restrict__ feats, const unsigned short* __restrict__ bt,
    const float* __restrict__ bias, float* __restrict__ out)
{
    __shared__ __align__(16) unsigned short Alds[2 * SLAB_SHORTS];   // 25088 B

    const int t    = threadIdx.x;
    const int lane = t & 63;
    const int w    = t >> 6;
    const int r16  = lane & 15;
    const int kg   = lane >> 4;

    // ---- B fragments into registers, once per block ----
    bf16x8 Bf0[NSTEP], Bf1[NSTEP];
    float bv0, bv1;
    {
        int c0 = w * 32 + r16, c1 = c0 + 16;
        bv0 = bias[c0]; bv1 = bias[c1];
        const unsigned short* p0 = bt + (size_t)c0 * KP + kg * 8;
        const unsigned short* p1 = bt + (size_t)c1 * KP + kg * 8;
        #pragma unroll
        for (int s = 0; s < NSTEP; ++s) {
            Bf0[s] = *reinterpret_cast<const bf16x8*>(p0 + s * 32);
            Bf1[s] = *reinterpret_cast<const bf16x8*>(p1 + s * 32);
        }
    }

    // ---- fixed staging geometry: thread t owns chunks q = i*256+t (16B each) ----
    bool sval[6];
    unsigned wa0[6], wa1[6];                 // packed LDS short-addresses
    #pragma unroll
    for (int i = 0; i < 6; ++i) {
        int q = i * 256 + t;
        sval[i] = (q < SLAB_CHUNKS);
        int qq = sval[i] ? q : 0;
        unsigned a[4];
        #pragma unroll
        for (int j = 0; j < 4; ++j) {
            int e   = qq * 4 + j;            // float index within slab
            int r   = e / F_TXN;
            int col = e - r * F_TXN;
            a[j] = (unsigned)(r * LROW + col);
        }
        wa0[i] = a[0] | (a[1] << 16);
        wa1[i] = a[2] | (a[3] << 16);
    }

    // ---- zero never-written cols 371..383 (read at s=11; B=0 there) ----
    for (int z = t; z < 2 * SLAB_ROWS * (KP - F_TXN); z += 256) {
        int b  = z / (SLAB_ROWS * (KP - F_TXN));
        int rm = z - b * (SLAB_ROWS * (KP - F_TXN));
        int r  = rm / (KP - F_TXN);
        int cc = rm - r * (KP - F_TXN);
        Alds[b * SLAB_SHORTS + r * LROW + F_TXN + cc] = 0;
    }

    f32x4 arA[6], arB[6];

    auto gload = [&](f32x4 (&ar)[6], int sl) {
        size_t S0 = (size_t)sl * SLAB_F32;   // 16B-aligned, exactly 1484 chunks
        #pragma unroll
        for (int i = 0; i < 6; ++i)
            if (sval[i])
                ar[i] = *reinterpret_cast<const f32x4*>(feats + S0 + (size_t)(i * 256 + t) * 4);
    };
    auto swrite = [&](int buf, const f32x4 (&ar)[6]) {
        unsigned short* dst = Alds + buf * SLAB_SHORTS;
        #pragma unroll
        for (int i = 0; i < 6; ++i)
            if (sval[i]) {
                dst[wa0[i] & 0xffffu] = f2bf(ar[i][0]);
                dst[wa0[i] >> 16]     = f2bf(ar[i][1]);
                dst[wa1[i] & 0xffffu] = f2bf(ar[i][2]);
                dst[wa1[i] >> 16]     = f2bf(ar[i][3]);
            }
    };

    const int bid = blockIdx.x;
    int sl  = bid;
    int cur = 0;

    // prologue: LDS[0] = slab bid; arA = slab bid+P in flight
    gload(arA, sl);
    swrite(0, arA);
    gload(arA, CLSLAB(sl + PBLK));
    __syncthreads();

    auto iter = [&](const f32x4 (&pend)[6], f32x4 (&tgt)[6]) {
        gload(tgt, CLSLAB(sl + 2 * PBLK));        // keep >=6 loads outstanding always
        __builtin_amdgcn_sched_barrier(0);        // don't sink below the vmcnt wait

        f32x4 acc0 = f32x4{0.f, 0.f, 0.f, 0.f};
        f32x4 acc1 = f32x4{0.f, 0.f, 0.f, 0.f};
        const unsigned short* Ar = Alds + cur * SLAB_SHORTS + r16 * LROW;
        #pragma unroll
        for (int s = 0; s < NSTEP; ++s) {         // conflict-free b128 reads
            bf16x8 af = *reinterpret_cast<const bf16x8*>(Ar + s * 32 + kg * 8);
            acc0 = __builtin_amdgcn_mfma_f32_16x16x32_bf16(af, Bf0[s], acc0, 0, 0, 0);
            acc1 = __builtin_amdgcn_mfma_f32_16x16x32_bf16(af, Bf1[s], acc1, 0, 0, 0);
        }

        swrite(cur ^ 1, pend);                    // waits only pend's (older) loads

        long R0 = (long)sl * SLAB_ROWS + kg * 4;  // C stores fly across the barrier
        int  c0 = w * 32 + r16;
        #pragma unroll
        for (int j = 0; j < 4; ++j) {
            float* o = out + (OUT_TXN_BASE + R0 + j) * HID;
            o[c0]      = acc0[j] + bv0;
            o[c0 + 16] = acc1[j] + bv1;
        }

        asm volatile("s_waitcnt lgkmcnt(0)" ::: "memory");   // LDS writes visible
        __builtin_amdgcn_s_barrier();             // no vmcnt drain
        __builtin_amdgcn_sched_barrier(0);
        cur ^= 1;
        sl  += PBLK;
    };

    while (sl < NSLAB) {
        iter(arA, arB);
        if (sl >= NSLAB) break;
        iter(arB, arA);
    }
}

extern "C" void kernel_launch(void* const* d_in, const int* in_sizes, int n_in,
                              void* d_out, int out_size, void* d_ws, size_t ws_size,
                              hipStream_t stream) {
    const float* cat_tables    = (const float*)d_in[0];
    const float* cont_w        = (const float*)d_in[1];
    const float* cont_b        = (const float*)d_in[2];
    const float* txn_w         = (const float*)d_in[3];
    const float* txn_b         = (const float*)d_in[4];
    const float* txn_feats     = (const float*)d_in[5];
    const float* cont_values   = (const float*)d_in[6];
    const int*   cat_type_ids  = (const int*)d_in[7];
    const int*   cat_value_ids = (const int*)d_in[8];
    const int*   cont_type_ids = (const int*)d_in[9];
    float* out = (float*)d_out;
    unsigned short* bt = (unsigned short*)d_ws;   // 128*384*2 = 96 KB

    bt_kernel<<<HID, KP, 0, stream>>>(txn_w, bt);
    txn_persist_kernel<<<PBLK, 256, 0, stream>>>(txn_feats, bt, txn_b, out);
    catcont_kernel<<<CAT_BLOCKS + CONT_BLOCKS, 256, 0, stream>>>(
        cat_tables, cat_type_ids, cat_value_ids,
        cont_w, cont_b, cont_values, cont_type_ids, out);
}